// Round 5
// baseline (222.508 us; speedup 1.0000x reference)
//
#include <hip/hip_runtime.h>
#include <hip/hip_bf16.h>
#include <math.h>

// GQA attention forward, MI355X. Round 5: fragment-major tiled GEMM operands +
// global_load_lds staging (m97-style), 128x128 GEMM tiles, BK=64, 1 barrier/k-iter.
// Tiled operand layout (per matrix [R][K=1024], bf16): tile = 128 rows x 64 k.
//   elem(row, k) at: ((tr*16 + tk)*8 + kc)*1024 + (row&127)*8 + (k&7)
//   where tr=row>>7, tk=k>>6, kc=(k&63)>>3.  A frag read = 16 consecutive bytes.
// ws (u16): Xq 2M | Xk 2M | Xv 2M | Wt 1.5M | wot 1M | Qr 2M | Kr 512K | Vrt 512K | AO 2M

#define SEQ 2048
#define DM 1024
#define HD 64

using u16 = unsigned short;
typedef __attribute__((ext_vector_type(8))) short bf16x8;
typedef __attribute__((ext_vector_type(4))) float f32x4;

// 1/sqrt(64) * log2(e): softmax in exp2 domain.
#define QSCALE 0.18033688011112042f

__device__ __forceinline__ u16 f2b(float f) {              // RNE
    union { float f; unsigned int i; } v; v.f = f;
    unsigned int u = v.i;
    return (u16)((u + 0x7fffu + ((u >> 16) & 1u)) >> 16);
}
__device__ __forceinline__ short f2b_fast(float f) {       // biased round
    union { float f; unsigned int i; } v; v.f = f;
    return (short)((v.i + 0x8000u) >> 16);
}

__device__ __forceinline__ void gl2lds16(const u16* g, u16* l) {
    __builtin_amdgcn_global_load_lds(
        (const __attribute__((address_space(1))) unsigned int*)g,
        (__attribute__((address_space(3))) unsigned int*)l, 16, 0, 0);
}

// ---------------------------------------------------------------- prep
// Blocks [0,640): weights 64x64 transpose fp32->bf16 into B-tiled layout.
//   [0,256) Wq->Wt rows 0..1023, [256,320) Wk->+1024, [320,384) Wv->+1280,
//   [384,640) Wo->wot.
// Blocks [640,2176): inputs q,k,v 64x64 fp32->bf16 into A-tiled layout.
__global__ __launch_bounds__(256) void prep_kernel(
    const float* __restrict__ qin, const float* __restrict__ kin, const float* __restrict__ vin,
    const float* __restrict__ Wq, const float* __restrict__ Wk,
    const float* __restrict__ Wv, const float* __restrict__ Wo,
    u16* __restrict__ Xq, u16* __restrict__ Xk, u16* __restrict__ Xv,
    u16* __restrict__ Wt, u16* __restrict__ wot)
{
    __shared__ short T[64][72];
    const int b = blockIdx.x;
    const int t = threadIdx.x;

    if (b < 640) {   // ---- weights: transpose to [n][k] then emit tiled
        const float* W; u16* dst; int N, t0, rowoff;
        if (b < 256)      { W = Wq; dst = Wt;  N = 1024; t0 = b;       rowoff = 0; }
        else if (b < 320) { W = Wk; dst = Wt;  N = 256;  t0 = b - 256; rowoff = 1024; }
        else if (b < 384) { W = Wv; dst = Wt;  N = 256;  t0 = b - 320; rowoff = 1280; }
        else              { W = Wo; dst = wot; N = 1024; t0 = b - 384; rowoff = 0; }
        const int ntn = N >> 6;
        const int k0 = (t0 / ntn) * 64, n0 = (t0 % ntn) * 64;
        const int r = t >> 4, c4 = (t & 15) * 4;
        #pragma unroll
        for (int rr = 0; rr < 4; ++rr) {
            const int k = r + rr * 16;
            float4 w4 = *reinterpret_cast<const float4*>(W + (size_t)(k0 + k) * N + n0 + c4);
            T[c4 + 0][k] = (short)f2b(w4.x);
            T[c4 + 1][k] = (short)f2b(w4.y);
            T[c4 + 2][k] = (short)f2b(w4.z);
            T[c4 + 3][k] = (short)f2b(w4.w);
        }
        __syncthreads();
        const int tk = k0 >> 6;
        #pragma unroll
        for (int p = 0; p < 2; ++p) {
            const int c = t + p * 256;            // 512 chunks: n in [0,64), kc in [0,8)
            const int n = c & 63, kc = c >> 6;
            const int ng = rowoff + n0 + n;
            const int nt = ng >> 7, nr = ng & 127;
            u16* dp = dst + ((size_t)((nt * 16 + tk) * 8 + kc)) * 1024 + nr * 8;
            *reinterpret_cast<bf16x8*>(dp) = *reinterpret_cast<const bf16x8*>(&T[n][kc * 8]);
        }
    } else {          // ---- inputs: convert to A-tiled layout
        const int idx = b - 640;
        const int which = idx >> 9;               // 512 blocks per input
        const int ib = idx & 511;
        const int m0 = (ib >> 4) * 64, tk = ib & 15, k0 = tk * 64;
        const float* src = (which == 0) ? qin : (which == 1) ? kin : vin;
        u16* dst = (which == 0) ? Xq : (which == 1) ? Xk : Xv;
        const int m = t >> 4, kq = (t & 15) * 4;
        #pragma unroll
        for (int mm = 0; mm < 4; ++mm) {
            const int ml = mm * 16 + m;
            float4 x4 = *reinterpret_cast<const float4*>(src + (size_t)(m0 + ml) * DM + k0 + kq);
            T[ml][kq + 0] = (short)f2b(x4.x);
            T[ml][kq + 1] = (short)f2b(x4.y);
            T[ml][kq + 2] = (short)f2b(x4.z);
            T[ml][kq + 3] = (short)f2b(x4.w);
        }
        __syncthreads();
        #pragma unroll
        for (int p = 0; p < 2; ++p) {
            const int c = t + p * 256;
            const int ml = c & 63, kc = c >> 6;
            const int mg = m0 + ml;
            const int tr = mg >> 7, mr = mg & 127;
            u16* dp = dst + ((size_t)((tr * 16 + tk) * 8 + kc)) * 1024 + mr * 8;
            *reinterpret_cast<bf16x8*>(dp) = *reinterpret_cast<const bf16x8*>(&T[ml][kc * 8]);
        }
    }
}

// ---------------------------------------------------------------- projections
// grid (12 nt, 16 mt): 128x128 tile, BK=64, dbuf LDS, global_load_lds staging.
// nt 0-7 = Q (RoPE*QSCALE), 8-9 = K (RoPE), 10-11 = V (transposed store).
__global__ __launch_bounds__(256) void proj_mfma(
    const u16* __restrict__ Xq, const u16* __restrict__ Xk, const u16* __restrict__ Xv,
    const u16* __restrict__ Wt,
    const float* __restrict__ bq, const float* __restrict__ bk, const float* __restrict__ bv,
    u16* __restrict__ Qr, u16* __restrict__ Kr, u16* __restrict__ Vrt)
{
    const int nt = blockIdx.x, mt = blockIdx.y;
    const int zone = (nt < 8) ? 0 : (nt < 10) ? 1 : 2;
    const u16* __restrict__ Az = (zone == 0) ? Xq : (zone == 1) ? Xk : Xv;

    __shared__ u16 As[2][8192];
    __shared__ u16 Bs[2][8192];

    const int t = threadIdx.x;
    const int w = t >> 6, lane = t & 63, lm = lane & 15, quad = lane >> 4;
    const int wy = w >> 1, wx = w & 1;

    f32x4 acc[4][4];
    #pragma unroll
    for (int i = 0; i < 4; ++i)
        #pragma unroll
        for (int j = 0; j < 4; ++j) acc[i][j] = (f32x4){0.f, 0.f, 0.f, 0.f};

    // stage tk=0 into buf 0
    {
        const u16* ga = Az + ((size_t)(mt * 16 + 0) << 13);
        const u16* gb = Wt + ((size_t)(nt * 16 + 0) << 13);
        #pragma unroll
        for (int g = 0; g < 4; ++g) {
            gl2lds16(ga + (size_t)(g * 256 + t) * 8, &As[0][(g * 256 + w * 64) * 8]);
            gl2lds16(gb + (size_t)(g * 256 + t) * 8, &Bs[0][(g * 256 + w * 64) * 8]);
        }
    }

    for (int tk = 0; tk < 16; ++tk) {
        const int buf = tk & 1;
        __syncthreads();   // drains staging vmcnt + separates prev reads from next writes
        if (tk < 15) {
            const u16* ga = Az + ((size_t)(mt * 16 + tk + 1) << 13);
            const u16* gb = Wt + ((size_t)(nt * 16 + tk + 1) << 13);
            #pragma unroll
            for (int g = 0; g < 4; ++g) {
                gl2lds16(ga + (size_t)(g * 256 + t) * 8, &As[buf ^ 1][(g * 256 + w * 64) * 8]);
                gl2lds16(gb + (size_t)(g * 256 + t) * 8, &Bs[buf ^ 1][(g * 256 + w * 64) * 8]);
            }
        }
        #pragma unroll
        for (int w2 = 0; w2 < 2; ++w2) {
            const int kc = w2 * 4 + quad;
            bf16x8 af[4], bfv[4];
            #pragma unroll
            for (int mb = 0; mb < 4; ++mb)
                af[mb] = *reinterpret_cast<const bf16x8*>(&As[buf][kc * 1024 + (wy * 64 + mb * 16 + lm) * 8]);
            #pragma unroll
            for (int nb = 0; nb < 4; ++nb)
                bfv[nb] = *reinterpret_cast<const bf16x8*>(&Bs[buf][kc * 1024 + (wx * 64 + nb * 16 + lm) * 8]);
            #pragma unroll
            for (int mb = 0; mb < 4; ++mb)
                #pragma unroll
                for (int nb = 0; nb < 4; ++nb)
                    acc[mb][nb] = __builtin_amdgcn_mfma_f32_16x16x32_bf16(af[mb], bfv[nb], acc[mb][nb], 0, 0, 0);
        }
    }

    // epilogue
    const float* __restrict__ bias = (zone == 0) ? bq : (zone == 1) ? bk : bv;
    const int zoff = (zone == 0) ? 0 : (zone == 1) ? 1024 : 1280;
    #pragma unroll
    for (int nb = 0; nb < 4; ++nb) {
        const int ncol = nt * 128 + wx * 64 + nb * 16 + lm;     // global col
        const int nl = ncol - zoff;                              // col within zone
        const int h = nl >> 6, d = nl & 63;
        const float bvv = bias[nl];
        if (zone != 2) {
            const int pi = d >> 1;
            const float theta = exp2f(-0.8304820237f * (float)pi);
            const bool odd = (d & 1);
            const float sca = (zone == 0) ? QSCALE : 1.0f;
            u16* op = (zone == 0 ? Qr : Kr) + (size_t)h * SEQ * HD;
            #pragma unroll
            for (int mb = 0; mb < 4; ++mb)
                #pragma unroll
                for (int r = 0; r < 4; ++r) {
                    const int m = mt * 128 + wy * 64 + mb * 16 + quad * 4 + r;
                    float x = acc[mb][nb][r] + bvv;
                    float sn, cs;
                    sincosf((float)m * theta, &sn, &cs);
                    float xp = __shfl_xor(x, 1);
                    float o = (odd ? (xp * sn + x * cs) : (x * cs - xp * sn)) * sca;
                    op[(size_t)m * HD + d] = f2b(o);
                }
        } else {
            #pragma unroll
            for (int mb = 0; mb < 4; ++mb) {
                const int m = mt * 128 + wy * 64 + mb * 16 + quad * 4;
                u16 pk[4];
                #pragma unroll
                for (int r = 0; r < 4; ++r) pk[r] = f2b(acc[mb][nb][r] + bvv);
                u16* vp = Vrt + ((size_t)h * HD + d) * SEQ + m;
                *reinterpret_cast<uint2*>(vp) = *reinterpret_cast<uint2*>(pk);
            }
        }
    }
}

// ---------------------------------------------------------------- attention
// grid (16 heads, 32). Fixed-base softmax (exp2), dbuf K/V, 1 barrier/k-tile.
// AO written in oproj's A-tiled layout.
__global__ __launch_bounds__(256) void attn_mfma(
    const u16* __restrict__ Qr, const u16* __restrict__ Kr, const u16* __restrict__ Vrt,
    u16* __restrict__ AO)
{
    const int h  = blockIdx.x;
    const int qy = blockIdx.y;
    const int qt = (qy < 16) ? (2 * qy) : (63 - 2 * qy);
    const int kvh = h & 3;

    __shared__ short QPs[64][72];       // Q staging (wave-private rows) then P
    __shared__ short Ks[2][64][72];
    __shared__ short Vt[2][64][72];     // [d][s]

    const int t = threadIdx.x;
    const int w = t >> 6, lane = t & 63, lm = lane & 15, quad = lane >> 4;
    const int sr = t >> 2, sc = (t & 3) * 16;

    {
        const u16* qp = Qr + ((size_t)h * SEQ + qt * 64 + sr) * HD + sc;
        *reinterpret_cast<bf16x8*>(&QPs[sr][sc])     = *reinterpret_cast<const bf16x8*>(qp);
        *reinterpret_cast<bf16x8*>(&QPs[sr][sc + 8]) = *reinterpret_cast<const bf16x8*>(qp + 8);
    }
    const bf16x8 aq0 = *reinterpret_cast<const bf16x8*>(&QPs[16 * w + lm][quad * 8]);
    const bf16x8 aq1 = *reinterpret_cast<const bf16x8*>(&QPs[16 * w + lm][32 + quad * 8]);

    f32x4 O[4] = { {0,0,0,0}, {0,0,0,0}, {0,0,0,0}, {0,0,0,0} };
    float l_i[4] = { 0.f, 0.f, 0.f, 0.f };

    const u16* kbase = Kr  + ((size_t)kvh * SEQ + sr) * HD + sc;
    const u16* vbase = Vrt + ((size_t)kvh * HD  + sr) * SEQ + sc;
    bf16x8 kA0 = *reinterpret_cast<const bf16x8*>(kbase);
    bf16x8 kA1 = *reinterpret_cast<const bf16x8*>(kbase + 8);
    bf16x8 vA0 = *reinterpret_cast<const bf16x8*>(vbase);
    bf16x8 vA1 = *reinterpret_cast<const bf16x8*>(vbase + 8);

    for (int kt = 0; kt <= qt; ++kt) {
        const int buf = kt & 1;
        *reinterpret_cast<bf16x8*>(&Ks[buf][sr][sc])     = kA0;
        *reinterpret_cast<bf16x8*>(&Ks[buf][sr][sc + 8]) = kA1;
        *reinterpret_cast<bf16x8*>(&Vt[buf][sr][sc])     = vA0;
        *reinterpret_cast<bf16x8*>(&Vt[buf][sr][sc + 8]) = vA1;
        if (kt < qt) {
            const u16* kp = kbase + (size_t)(kt + 1) * 64 * HD;
            const u16* vp = vbase + (size_t)(kt + 1) * 64;
            kA0 = *reinterpret_cast<const bf16x8*>(kp);
            kA1 = *reinterpret_cast<const bf16x8*>(kp + 8);
            vA0 = *reinterpret_cast<const bf16x8*>(vp);
            vA1 = *reinterpret_cast<const bf16x8*>(vp + 8);
        }
        __syncthreads();

        f32x4 s[4];
        #pragma unroll
        for (int nb = 0; nb < 4; ++nb) {
            bf16x8 b0 = *reinterpret_cast<const bf16x8*>(&Ks[buf][16 * nb + lm][quad * 8]);
            bf16x8 b1 = *reinterpret_cast<const bf16x8*>(&Ks[buf][16 * nb + lm][32 + quad * 8]);
            f32x4 zz = { 0.f, 0.f, 0.f, 0.f };
            zz = __builtin_amdgcn_mfma_f32_16x16x32_bf16(aq0, b0, zz, 0, 0, 0);
            s[nb] = __builtin_amdgcn_mfma_f32_16x16x32_bf16(aq1, b1, zz, 0, 0, 0);
        }

        if (kt == qt) {
            #pragma unroll
            for (int nb = 0; nb < 4; ++nb)
                #pragma unroll
                for (int r = 0; r < 4; ++r)
                    if (16 * nb + lm > 16 * w + quad * 4 + r) s[nb][r] = -INFINITY;
        }

        #pragma unroll
        for (int nb = 0; nb < 4; ++nb)
            #pragma unroll
            for (int r = 0; r < 4; ++r) {
                float e = __builtin_amdgcn_exp2f(fminf(s[nb][r], 126.f));
                l_i[r] += e;
                QPs[16 * w + quad * 4 + r][16 * nb + lm] = f2b_fast(e);
            }

        bf16x8 ap0 = *reinterpret_cast<const bf16x8*>(&QPs[16 * w + lm][quad * 8]);
        bf16x8 ap1 = *reinterpret_cast<const bf16x8*>(&QPs[16 * w + lm][32 + quad * 8]);
        #pragma unroll
        for (int db = 0; db < 4; ++db) {
            bf16x8 b0 = *reinterpret_cast<const bf16x8*>(&Vt[buf][16 * db + lm][quad * 8]);
            bf16x8 b1 = *reinterpret_cast<const bf16x8*>(&Vt[buf][16 * db + lm][32 + quad * 8]);
            O[db] = __builtin_amdgcn_mfma_f32_16x16x32_bf16(ap0, b0, O[db], 0, 0, 0);
            O[db] = __builtin_amdgcn_mfma_f32_16x16x32_bf16(ap1, b1, O[db], 0, 0, 0);
        }
    }

    #pragma unroll
    for (int r = 0; r < 4; ++r) {
        float lr = l_i[r];
        #pragma unroll
        for (int off = 1; off < 16; off <<= 1)
            lr += __shfl_xor(lr, off);
        const float inv = 1.0f / lr;
        const int row = qt * 64 + 16 * w + quad * 4 + r;
        const int tr = row >> 7, mr = row & 127;
        const int j = lm & 7;
        #pragma unroll
        for (int db = 0; db < 4; ++db) {
            const int kc = 2 * db + (lm >> 3);
            AO[((size_t)((tr * 16 + h) * 8 + kc)) * 1024 + mr * 8 + j] = f2b(O[db][r] * inv);
        }
    }
}

// ---------------------------------------------------------------- output proj
// grid (8 nt, 16 mt): AO(tiled bf16) @ wot(tiled bf16) + bo -> fp32 out.
__global__ __launch_bounds__(256) void oproj_mfma(
    const u16* __restrict__ AO, const u16* __restrict__ wot,
    const float* __restrict__ bo, float* __restrict__ out)
{
    const int nt = blockIdx.x, mt = blockIdx.y;

    __shared__ u16 As[2][8192];
    __shared__ u16 Bs[2][8192];

    const int t = threadIdx.x;
    const int w = t >> 6, lane = t & 63, lm = lane & 15, quad = lane >> 4;
    const int wy = w >> 1, wx = w & 1;

    f32x4 acc[4][4];
    #pragma unroll
    for (int i = 0; i < 4; ++i)
        #pragma unroll
        for (int j = 0; j < 4; ++j) acc[i][j] = (f32x4){0.f, 0.f, 0.f, 0.f};

    {
        const u16* ga = AO  + ((size_t)(mt * 16 + 0) << 13);
        const u16* gb = wot + ((size_t)(nt * 16 + 0) << 13);
        #pragma unroll
        for (int g = 0; g < 4; ++g) {
            gl2lds16(ga + (size_t)(g * 256 + t) * 8, &As[0][(g * 256 + w * 64) * 8]);
            gl2lds16(gb + (size_t)(g * 256 + t) * 8, &Bs[0][(g * 256 + w * 64) * 8]);
        }
    }

    for (int tk = 0; tk < 16; ++tk) {
        const int buf = tk & 1;
        __syncthreads();
        if (tk < 15) {
            const u16* ga = AO  + ((size_t)(mt * 16 + tk + 1) << 13);
            const u16* gb = wot + ((size_t)(nt * 16 + tk + 1) << 13);
            #pragma unroll
            for (int g = 0; g < 4; ++g) {
                gl2lds16(ga + (size_t)(g * 256 + t) * 8, &As[buf ^ 1][(g * 256 + w * 64) * 8]);
                gl2lds16(gb + (size_t)(g * 256 + t) * 8, &Bs[buf ^ 1][(g * 256 + w * 64) * 8]);
            }
        }
        #pragma unroll
        for (int w2 = 0; w2 < 2; ++w2) {
            const int kc = w2 * 4 + quad;
            bf16x8 af[4], bfv[4];
            #pragma unroll
            for (int mb = 0; mb < 4; ++mb)
                af[mb] = *reinterpret_cast<const bf16x8*>(&As[buf][kc * 1024 + (wy * 64 + mb * 16 + lm) * 8]);
            #pragma unroll
            for (int nb = 0; nb < 4; ++nb)
                bfv[nb] = *reinterpret_cast<const bf16x8*>(&Bs[buf][kc * 1024 + (wx * 64 + nb * 16 + lm) * 8]);
            #pragma unroll
            for (int mb = 0; mb < 4; ++mb)
                #pragma unroll
                for (int nb = 0; nb < 4; ++nb)
                    acc[mb][nb] = __builtin_amdgcn_mfma_f32_16x16x32_bf16(af[mb], bfv[nb], acc[mb][nb], 0, 0, 0);
        }
    }

    #pragma unroll
    for (int nb = 0; nb < 4; ++nb) {
        const int ncol = nt * 128 + wx * 64 + nb * 16 + lm;
        const float bvv = bo[ncol];
        #pragma unroll
        for (int mb = 0; mb < 4; ++mb)
            #pragma unroll
            for (int r = 0; r < 4; ++r) {
                const int m = mt * 128 + wy * 64 + mb * 16 + quad * 4 + r;
                out[(size_t)m * DM + ncol] = acc[mb][nb][r] + bvv;
            }
    }
}

// ---------------------------------------------------------------- launcher
extern "C" void kernel_launch(void* const* d_in, const int* in_sizes, int n_in,
                              void* d_out, int out_size, void* d_ws, size_t ws_size,
                              hipStream_t stream)
{
    const float* q  = (const float*)d_in[0];
    const float* k  = (const float*)d_in[1];
    const float* v  = (const float*)d_in[2];
    // d_in[3] = mask (int32) — causal tril, handled analytically
    const float* Wq = (const float*)d_in[4];
    const float* bq = (const float*)d_in[5];
    const float* Wk = (const float*)d_in[6];
    const float* bk = (const float*)d_in[7];
    const float* Wv = (const float*)d_in[8];
    const float* bv = (const float*)d_in[9];
    const float* Wo = (const float*)d_in[10];
    const float* bo = (const float*)d_in[11];
    float* out = (float*)d_out;

    u16* Xq  = (u16*)d_ws;                          // 2048*1024 (tiled)
    u16* Xk  = Xq  + (size_t)SEQ * DM;
    u16* Xv  = Xk  + (size_t)SEQ * DM;
    u16* Wt  = Xv  + (size_t)SEQ * DM;              // 1536*1024 (tiled)
    u16* wot = Wt  + (size_t)1536 * 1024;           // 1024*1024 (tiled)
    u16* Qr  = wot + (size_t)1024 * 1024;           // [16][2048][64]
    u16* Kr  = Qr  + (size_t)16 * SEQ * HD;         // [4][2048][64]
    u16* Vrt = Kr  + (size_t)4 * SEQ * HD;          // [4][64][2048]
    u16* AO  = Vrt + (size_t)4 * SEQ * HD;          // 2048*1024 (tiled)

    hipLaunchKernelGGL(prep_kernel, dim3(2176), dim3(256), 0, stream,
                       q, k, v, Wq, Wk, Wv, Wo, Xq, Xk, Xv, Wt, wot);
    hipLaunchKernelGGL(proj_mfma, dim3(12, 16), dim3(256), 0, stream,
                       Xq, Xk, Xv, Wt, bq, bk, bv, Qr, Kr, Vrt);
    hipLaunchKernelGGL(attn_mfma, dim3(16, 32), dim3(256), 0, stream,
                       Qr, Kr, Vrt, AO);
    hipLaunchKernelGGL(oproj_mfma, dim3(8, 16), dim3(256), 0, stream,
                       AO, wot, bo, out);
}

// Round 6
// 184.017 us; speedup vs baseline: 1.2092x; 1.2092x over previous
//
#include <hip/hip_runtime.h>
#include <hip/hip_bf16.h>
#include <math.h>

// GQA attention forward, MI355X. Round 6: r4 GEMM structure (64x64, BK=64,
// high occupancy) + bf16-preconverted activations + transposed-attention
// rewrite (S^T = K Q^T, O^T = V^T P^T, P in-LDS packed, Q-frags hoisted,
// fixed-base exp2 softmax, cross-wave epilogue reduction).
// ws (u16): Xq 2M | Xk 2M | Xv 2M | Wt 1.5M | wot 1M | Qr 2M | Kr 512K | Vrt 512K | AO 2M

#define SEQ 2048
#define DM 1024
#define HD 64

using u16 = unsigned short;
typedef __attribute__((ext_vector_type(8))) short bf16x8;
typedef __attribute__((ext_vector_type(4))) float f32x4;

// 1/sqrt(64) * log2(e): softmax in exp2 domain.
#define QSCALE 0.18033688011112042f

__device__ __forceinline__ u16 f2b(float f) {              // RNE
    union { float f; unsigned int i; } v; v.f = f;
    unsigned int u = v.i;
    return (u16)((u + 0x7fffu + ((u >> 16) & 1u)) >> 16);
}
__device__ __forceinline__ u16 f2b_fast(float f) {         // biased round
    union { float f; unsigned int i; } v; v.f = f;
    return (u16)((v.i + 0x8000u) >> 16);
}

// ---------------------------------------------------------------- prep
// [0,640): weight 64x64 transposes fp32->bf16: Wq->Wt[0..1023], Wk->Wt[+1024],
//          Wv->Wt[+1280], Wo->wot. Row-major [n][k].
// [640,1408): q/k/v fp32 -> bf16 row-major (256 blocks each, 8192 elem/block).
__global__ __launch_bounds__(256) void prep_kernel(
    const float* __restrict__ qin, const float* __restrict__ kin, const float* __restrict__ vin,
    const float* __restrict__ Wq, const float* __restrict__ Wk,
    const float* __restrict__ Wv, const float* __restrict__ Wo,
    u16* __restrict__ Xq, u16* __restrict__ Xk, u16* __restrict__ Xv,
    u16* __restrict__ Wt, u16* __restrict__ wot)
{
    const int b = blockIdx.x;
    const int t = threadIdx.x;

    if (b < 640) {
        __shared__ short T[64][72];
        const float* W; u16* dst; int N, t0, rowoff;
        if (b < 256)      { W = Wq; dst = Wt;  N = 1024; t0 = b;       rowoff = 0; }
        else if (b < 320) { W = Wk; dst = Wt;  N = 256;  t0 = b - 256; rowoff = 1024; }
        else if (b < 384) { W = Wv; dst = Wt;  N = 256;  t0 = b - 320; rowoff = 1280; }
        else              { W = Wo; dst = wot; N = 1024; t0 = b - 384; rowoff = 0; }
        const int ntn = N >> 6;
        const int k0 = (t0 / ntn) * 64, n0 = (t0 % ntn) * 64;
        const int r = t >> 4, c4 = (t & 15) * 4;
        #pragma unroll
        for (int rr = 0; rr < 4; ++rr) {
            const int k = r + rr * 16;
            float4 w4 = *reinterpret_cast<const float4*>(W + (size_t)(k0 + k) * N + n0 + c4);
            T[c4 + 0][k] = (short)f2b(w4.x);
            T[c4 + 1][k] = (short)f2b(w4.y);
            T[c4 + 2][k] = (short)f2b(w4.z);
            T[c4 + 3][k] = (short)f2b(w4.w);
        }
        __syncthreads();
        const int n = t >> 2, ck = (t & 3) * 16;
        u16* dp = dst + (size_t)(rowoff + n0 + n) * DM + k0 + ck;
        *reinterpret_cast<bf16x8*>(dp)     = *reinterpret_cast<const bf16x8*>(&T[n][ck]);
        *reinterpret_cast<bf16x8*>(dp + 8) = *reinterpret_cast<const bf16x8*>(&T[n][ck + 8]);
    } else {
        const int idx = b - 640;
        const int which = idx >> 8;                 // 256 blocks per tensor
        const int ib = idx & 255;
        const float* src = (which == 0) ? qin : (which == 1) ? kin : vin;
        u16* dst = (which == 0) ? Xq : (which == 1) ? Xk : Xv;
        const size_t base = (size_t)ib * 8192 + (size_t)t * 32;
        #pragma unroll
        for (int c = 0; c < 4; ++c) {
            float4 x0 = *reinterpret_cast<const float4*>(src + base + c * 8);
            float4 x1 = *reinterpret_cast<const float4*>(src + base + c * 8 + 4);
            bf16x8 o;
            o[0] = (short)f2b(x0.x); o[1] = (short)f2b(x0.y);
            o[2] = (short)f2b(x0.z); o[3] = (short)f2b(x0.w);
            o[4] = (short)f2b(x1.x); o[5] = (short)f2b(x1.y);
            o[6] = (short)f2b(x1.z); o[7] = (short)f2b(x1.w);
            *reinterpret_cast<bf16x8*>(dst + base + c * 8) = o;
        }
    }
}

// ---------------------------------------------------------------- projections
// Unified QKV GEMM: grid (24, 32), 64x64 tile, BK=64. A pre-converted bf16.
// Cols [0,1024)=Q (RoPE*QSCALE), [1024,1280)=K (RoPE), [1280,1536)=V (transposed).
__global__ __launch_bounds__(256) void proj_mfma(
    const u16* __restrict__ Xq, const u16* __restrict__ Xk, const u16* __restrict__ Xv,
    const u16* __restrict__ Wt,
    const float* __restrict__ bq, const float* __restrict__ bk, const float* __restrict__ bv,
    u16* __restrict__ Qr, u16* __restrict__ Kr, u16* __restrict__ Vrt)
{
    const int n0 = blockIdx.x * 64, m0 = blockIdx.y * 64;
    const int zone = (n0 < 1024) ? 0 : (n0 < 1280) ? 1 : 2;
    const u16* __restrict__ Az = (zone == 0) ? Xq : (zone == 1) ? Xk : Xv;

    __shared__ short As[64][72];
    __shared__ short Bs[64][72];

    const int t = threadIdx.x;
    const int w = t >> 6, lane = t & 63, lm = lane & 15, quad = lane >> 4;
    const int sr = t >> 2, sc = (t & 3) * 16;

    f32x4 acc[4] = { {0,0,0,0}, {0,0,0,0}, {0,0,0,0}, {0,0,0,0} };

    for (int k0 = 0; k0 < DM; k0 += 64) {
        const u16* ap = Az + (size_t)(m0 + sr) * DM + k0 + sc;
        *reinterpret_cast<bf16x8*>(&As[sr][sc])     = *reinterpret_cast<const bf16x8*>(ap);
        *reinterpret_cast<bf16x8*>(&As[sr][sc + 8]) = *reinterpret_cast<const bf16x8*>(ap + 8);
        const u16* bp = Wt + (size_t)(n0 + sr) * DM + k0 + sc;
        *reinterpret_cast<bf16x8*>(&Bs[sr][sc])     = *reinterpret_cast<const bf16x8*>(bp);
        *reinterpret_cast<bf16x8*>(&Bs[sr][sc + 8]) = *reinterpret_cast<const bf16x8*>(bp + 8);
        __syncthreads();
        bf16x8 af0 = *reinterpret_cast<const bf16x8*>(&As[16 * w + lm][quad * 8]);
        bf16x8 af1 = *reinterpret_cast<const bf16x8*>(&As[16 * w + lm][32 + quad * 8]);
        #pragma unroll
        for (int nb = 0; nb < 4; ++nb) {
            bf16x8 b0 = *reinterpret_cast<const bf16x8*>(&Bs[16 * nb + lm][quad * 8]);
            bf16x8 b1 = *reinterpret_cast<const bf16x8*>(&Bs[16 * nb + lm][32 + quad * 8]);
            acc[nb] = __builtin_amdgcn_mfma_f32_16x16x32_bf16(af0, b0, acc[nb], 0, 0, 0);
            acc[nb] = __builtin_amdgcn_mfma_f32_16x16x32_bf16(af1, b1, acc[nb], 0, 0, 0);
        }
        __syncthreads();
    }

    const float* __restrict__ bias = (zone == 0) ? bq : (zone == 1) ? bk : bv;
    const int nbase = (zone == 0) ? n0 : (zone == 1) ? (n0 - 1024) : (n0 - 1280);
    const int head = nbase >> 6;
    #pragma unroll
    for (int nb = 0; nb < 4; ++nb) {
        const int d = 16 * nb + lm;
        const float bvv = bias[nbase + d];
        float vals[4];
        #pragma unroll
        for (int r = 0; r < 4; ++r) vals[r] = acc[nb][r] + bvv;
        if (zone != 2) {
            const int pi = d >> 1;
            const float theta = exp2f(-0.8304820237f * (float)pi);  // 10000^(-pi/16)
            const bool odd = (lm & 1);
            const float sca = (zone == 0) ? QSCALE : 1.0f;
            #pragma unroll
            for (int r = 0; r < 4; ++r) {
                const int m = m0 + 16 * w + quad * 4 + r;
                float sn, cs;
                sincosf((float)m * theta, &sn, &cs);
                float x  = vals[r];
                float xp = __shfl_xor(x, 1);
                vals[r] = (odd ? (xp * sn + x * cs) : (x * cs - xp * sn)) * sca;
            }
            u16* op = (zone == 0 ? Qr : Kr) + (size_t)head * SEQ * HD;
            #pragma unroll
            for (int r = 0; r < 4; ++r) {
                const int m = m0 + 16 * w + quad * 4 + r;
                op[(size_t)m * HD + d] = f2b(vals[r]);
            }
        } else {      // V transposed [kvh][d][s]
            u16 pk[4];
            #pragma unroll
            for (int r = 0; r < 4; ++r) pk[r] = f2b(vals[r]);
            u16* vp = Vrt + ((size_t)head * HD + d) * SEQ + m0 + 16 * w + quad * 4;
            *reinterpret_cast<uint2*>(vp) = *reinterpret_cast<uint2*>(pk);
        }
    }
}

// ---------------------------------------------------------------- attention
// grid (16 heads, 32 qy). Transposed: per tile-pair, wave w owns key strip
// [16w,16w+16) of each tile. S^T = K Q^T (Q B-frags hoisted), P^T packed to
// LDS [q][keycol] (keycol = w*32 + tp*16 + s), O^T += V^T P^T with K=32.
// Fixed-base exp2 softmax; cross-wave O^T/l reduction in epilogue.
__global__ __launch_bounds__(256) void attn_mfma(
    const u16* __restrict__ Qr, const u16* __restrict__ Kr, const u16* __restrict__ Vrt,
    u16* __restrict__ AO)
{
    const int h  = blockIdx.x;
    const int qy = blockIdx.y;
    const int qt = (qy < 16) ? (2 * qy) : (63 - 2 * qy);   // balanced pairing
    const int kvh = h & 3;

    __shared__ short Qs[64][72];
    __shared__ short Ks[2][64][72];      // [tile][key][d]
    __shared__ short Vt[64][136];        // [d][keycol]
    __shared__ short Ps[64][136];        // [q][keycol]; epilogue: float [64][68]
    __shared__ float Lred[4][64];

    const int t = threadIdx.x;
    const int w = t >> 6, lane = t & 63, lm = lane & 15, quad = lane >> 4;
    const int sr = t >> 2, sc = (t & 3) * 16;
    const int colb = (sc >> 4) * 32;     // V staging col base (tp=0)

    {   // stage Q tile
        const u16* qp = Qr + ((size_t)h * SEQ + qt * 64 + sr) * HD + sc;
        *reinterpret_cast<bf16x8*>(&Qs[sr][sc])     = *reinterpret_cast<const bf16x8*>(qp);
        *reinterpret_cast<bf16x8*>(&Qs[sr][sc + 8]) = *reinterpret_cast<const bf16x8*>(qp + 8);
    }
    __syncthreads();
    bf16x8 bq[4][2];                     // hoisted Q B-frags: B[k=d][n=q]
    #pragma unroll
    for (int nb = 0; nb < 4; ++nb) {
        bq[nb][0] = *reinterpret_cast<const bf16x8*>(&Qs[16 * nb + lm][quad * 8]);
        bq[nb][1] = *reinterpret_cast<const bf16x8*>(&Qs[16 * nb + lm][32 + quad * 8]);
    }

    f32x4 O[4][4];                       // O^T partial: [db][nb]
    #pragma unroll
    for (int i = 0; i < 4; ++i)
        #pragma unroll
        for (int j = 0; j < 4; ++j) O[i][j] = (f32x4){0.f, 0.f, 0.f, 0.f};
    float lp[4] = { 0.f, 0.f, 0.f, 0.f };

    const int ntile = qt + 1;
    const u16* kbase = Kr  + ((size_t)kvh * SEQ + sr) * HD + sc;
    const u16* vbase = Vrt + ((size_t)kvh * HD  + sr) * SEQ + sc;

    for (int u = 0; u < ntile; u += 2) {
        const bool has1 = (u + 1 < ntile);
        {   // stage K tiles + V pair
            const u16* kp0 = kbase + (size_t)u * 64 * HD;
            *reinterpret_cast<bf16x8*>(&Ks[0][sr][sc])     = *reinterpret_cast<const bf16x8*>(kp0);
            *reinterpret_cast<bf16x8*>(&Ks[0][sr][sc + 8]) = *reinterpret_cast<const bf16x8*>(kp0 + 8);
            const u16* vp0 = vbase + (size_t)u * 64;
            *reinterpret_cast<bf16x8*>(&Vt[sr][colb])      = *reinterpret_cast<const bf16x8*>(vp0);
            *reinterpret_cast<bf16x8*>(&Vt[sr][colb + 8])  = *reinterpret_cast<const bf16x8*>(vp0 + 8);
            if (has1) {
                const u16* kp1 = kbase + (size_t)(u + 1) * 64 * HD;
                *reinterpret_cast<bf16x8*>(&Ks[1][sr][sc])     = *reinterpret_cast<const bf16x8*>(kp1);
                *reinterpret_cast<bf16x8*>(&Ks[1][sr][sc + 8]) = *reinterpret_cast<const bf16x8*>(kp1 + 8);
                const u16* vp1 = vbase + (size_t)(u + 1) * 64;
                *reinterpret_cast<bf16x8*>(&Vt[sr][colb + 16]) = *reinterpret_cast<const bf16x8*>(vp1);
                *reinterpret_cast<bf16x8*>(&Vt[sr][colb + 24]) = *reinterpret_cast<const bf16x8*>(vp1 + 8);
            } else {
                bf16x8 z = {0,0,0,0,0,0,0,0};
                *reinterpret_cast<bf16x8*>(&Vt[sr][colb + 16]) = z;
                *reinterpret_cast<bf16x8*>(&Vt[sr][colb + 24]) = z;
            }
        }
        __syncthreads();

        #pragma unroll
        for (int tp = 0; tp < 2; ++tp) {
            const int kt = u + tp;
            if (tp == 1 && !has1) {       // zero P cols for missing tile
                const uint2 z2 = make_uint2(0u, 0u);
                #pragma unroll
                for (int nb = 0; nb < 4; ++nb)
                    *reinterpret_cast<uint2*>(&Ps[16 * nb + lm][w * 32 + 16 + quad * 4]) = z2;
                continue;
            }
            const bf16x8 ak0 = *reinterpret_cast<const bf16x8*>(&Ks[tp][16 * w + lm][quad * 8]);
            const bf16x8 ak1 = *reinterpret_cast<const bf16x8*>(&Ks[tp][16 * w + lm][32 + quad * 8]);
            const bool diag = (kt == qt);
            #pragma unroll
            for (int nb = 0; nb < 4; ++nb) {
                f32x4 ss = { 0.f, 0.f, 0.f, 0.f };
                ss = __builtin_amdgcn_mfma_f32_16x16x32_bf16(ak0, bq[nb][0], ss, 0, 0, 0);
                ss = __builtin_amdgcn_mfma_f32_16x16x32_bf16(ak1, bq[nb][1], ss, 0, 0, 0);
                u16 pk[4];
                #pragma unroll
                for (int r = 0; r < 4; ++r) {
                    float sv = ss[r];
                    if (diag && (16 * w + quad * 4 + r > 16 * nb + lm)) sv = -INFINITY;
                    float e = __builtin_amdgcn_exp2f(fminf(sv, 126.f));
                    lp[nb] += e;
                    pk[r] = f2b_fast(e);
                }
                *reinterpret_cast<uint2*>(&Ps[16 * nb + lm][w * 32 + tp * 16 + quad * 4]) =
                    *reinterpret_cast<uint2*>(pk);
            }
        }

        // PV: O^T += V^T[d][32 keys] * P^T[32 keys][q]  (wave-private key cols)
        #pragma unroll
        for (int db = 0; db < 4; ++db) {
            const bf16x8 av = *reinterpret_cast<const bf16x8*>(&Vt[16 * db + lm][w * 32 + quad * 8]);
            #pragma unroll
            for (int nb = 0; nb < 4; ++nb) {
                const bf16x8 bp = *reinterpret_cast<const bf16x8*>(&Ps[16 * nb + lm][w * 32 + quad * 8]);
                O[db][nb] = __builtin_amdgcn_mfma_f32_16x16x32_bf16(av, bp, O[db][nb], 0, 0, 0);
            }
        }
        __syncthreads();   // before restaging Ks/Vt/Ps
    }

    // l: reduce across quads (lanes differ in bits 4..5), publish per wave
    #pragma unroll
    for (int nb = 0; nb < 4; ++nb) {
        lp[nb] += __shfl_xor(lp[nb], 16);
        lp[nb] += __shfl_xor(lp[nb], 32);
    }
    if (quad == 0) {
        #pragma unroll
        for (int nb = 0; nb < 4; ++nb) Lred[w][16 * nb + lm] = lp[nb];
    }

    // O^T: 4-phase cross-wave accumulation into float scratch (overlays Ps)
    float* Sf = reinterpret_cast<float*>(&Ps[0][0]);     // [64 q][68 d]
    #pragma unroll
    for (int ph = 0; ph < 4; ++ph) {
        __syncthreads();
        if (w == ph) {
            #pragma unroll
            for (int db = 0; db < 4; ++db)
                #pragma unroll
                for (int nb = 0; nb < 4; ++nb)
                    #pragma unroll
                    for (int r = 0; r < 4; ++r) {
                        const int d = 16 * db + quad * 4 + r, q = 16 * nb + lm;
                        const float v = O[db][nb][r];
                        Sf[q * 68 + d] = (ph == 0) ? v : (Sf[q * 68 + d] + v);
                    }
        }
    }
    __syncthreads();

    {   // AO[qt*64+q][h*64+dc..] = Sf[q][.] / l[q]
        const int q = t >> 2, dc = (t & 3) * 16;
        const float linv = 1.0f / (Lred[0][q] + Lred[1][q] + Lred[2][q] + Lred[3][q]);
        u16 pk[16];
        #pragma unroll
        for (int j = 0; j < 16; ++j)
            pk[j] = f2b(Sf[q * 68 + dc + j] * linv);
        u16* op = AO + (size_t)(qt * 64 + q) * DM + h * HD + dc;
        *reinterpret_cast<bf16x8*>(op)     = *reinterpret_cast<const bf16x8*>(pk);
        *reinterpret_cast<bf16x8*>(op + 8) = *reinterpret_cast<const bf16x8*>(pk + 8);
    }
}

// ---------------------------------------------------------------- output proj
// grid (16, 32): AO bf16 @ Wo^T bf16 + bo -> fp32 out. BK=64.
__global__ __launch_bounds__(256) void oproj_mfma(
    const u16* __restrict__ AO, const u16* __restrict__ wot,
    const float* __restrict__ bo, float* __restrict__ out)
{
    __shared__ short As[64][72];
    __shared__ short Bs[64][72];
    const int t = threadIdx.x;
    const int w = t >> 6, lane = t & 63, lm = lane & 15, quad = lane >> 4;
    const int m0 = blockIdx.y * 64, n0 = blockIdx.x * 64;
    const int sr = t >> 2, sc = (t & 3) * 16;

    f32x4 acc[4] = { {0,0,0,0}, {0,0,0,0}, {0,0,0,0}, {0,0,0,0} };

    for (int k0 = 0; k0 < DM; k0 += 64) {
        const u16* ap = AO + (size_t)(m0 + sr) * DM + k0 + sc;
        *reinterpret_cast<bf16x8*>(&As[sr][sc])     = *reinterpret_cast<const bf16x8*>(ap);
        *reinterpret_cast<bf16x8*>(&As[sr][sc + 8]) = *reinterpret_cast<const bf16x8*>(ap + 8);
        const u16* bp = wot + (size_t)(n0 + sr) * DM + k0 + sc;
        *reinterpret_cast<bf16x8*>(&Bs[sr][sc])     = *reinterpret_cast<const bf16x8*>(bp);
        *reinterpret_cast<bf16x8*>(&Bs[sr][sc + 8]) = *reinterpret_cast<const bf16x8*>(bp + 8);
        __syncthreads();
        bf16x8 af0 = *reinterpret_cast<const bf16x8*>(&As[16 * w + lm][quad * 8]);
        bf16x8 af1 = *reinterpret_cast<const bf16x8*>(&As[16 * w + lm][32 + quad * 8]);
        #pragma unroll
        for (int nb = 0; nb < 4; ++nb) {
            bf16x8 b0 = *reinterpret_cast<const bf16x8*>(&Bs[16 * nb + lm][quad * 8]);
            bf16x8 b1 = *reinterpret_cast<const bf16x8*>(&Bs[16 * nb + lm][32 + quad * 8]);
            acc[nb] = __builtin_amdgcn_mfma_f32_16x16x32_bf16(af0, b0, acc[nb], 0, 0, 0);
            acc[nb] = __builtin_amdgcn_mfma_f32_16x16x32_bf16(af1, b1, acc[nb], 0, 0, 0);
        }
        __syncthreads();
    }

    #pragma unroll
    for (int nb = 0; nb < 4; ++nb) {
        const int dl = 16 * nb + lm;
        const float bv = bo[n0 + dl];
        #pragma unroll
        for (int r = 0; r < 4; ++r) {
            const int m = m0 + 16 * w + quad * 4 + r;
            out[(size_t)m * DM + n0 + dl] = acc[nb][r] + bv;
        }
    }
}

// ---------------------------------------------------------------- launcher
extern "C" void kernel_launch(void* const* d_in, const int* in_sizes, int n_in,
                              void* d_out, int out_size, void* d_ws, size_t ws_size,
                              hipStream_t stream)
{
    const float* q  = (const float*)d_in[0];
    const float* k  = (const float*)d_in[1];
    const float* v  = (const float*)d_in[2];
    // d_in[3] = mask (int32) — causal tril, handled analytically
    const float* Wq = (const float*)d_in[4];
    const float* bq = (const float*)d_in[5];
    const float* Wk = (const float*)d_in[6];
    const float* bk = (const float*)d_in[7];
    const float* Wv = (const float*)d_in[8];
    const float* bv = (const float*)d_in[9];
    const float* Wo = (const float*)d_in[10];
    const float* bo = (const float*)d_in[11];
    float* out = (float*)d_out;

    u16* Xq  = (u16*)d_ws;                          // 2048*1024 bf16 row-major
    u16* Xk  = Xq  + (size_t)SEQ * DM;
    u16* Xv  = Xk  + (size_t)SEQ * DM;
    u16* Wt  = Xv  + (size_t)SEQ * DM;              // [1536][1024]
    u16* wot = Wt  + (size_t)1536 * 1024;           // [1024][1024]
    u16* Qr  = wot + (size_t)1024 * 1024;           // [16][2048][64]
    u16* Kr  = Qr  + (size_t)16 * SEQ * HD;         // [4][2048][64]
    u16* Vrt = Kr  + (size_t)4 * SEQ * HD;          // [4][64][2048]
    u16* AO  = Vrt + (size_t)4 * SEQ * HD;          // [2048][1024]

    hipLaunchKernelGGL(prep_kernel, dim3(1408), dim3(256), 0, stream,
                       q, k, v, Wq, Wk, Wv, Wo, Xq, Xk, Xv, Wt, wot);
    hipLaunchKernelGGL(proj_mfma, dim3(24, 32), dim3(256), 0, stream,
                       Xq, Xk, Xv, Wt, bq, bk, bv, Qr, Kr, Vrt);
    hipLaunchKernelGGL(attn_mfma, dim3(16, 32), dim3(256), 0, stream,
                       Qr, Kr, Vrt, AO);
    hipLaunchKernelGGL(oproj_mfma, dim3(16, 32), dim3(256), 0, stream,
                       AO, wot, bo, out);
}